// Round 1
// baseline (1216.163 us; speedup 1.0000x reference)
//
#include <hip/hip_runtime.h>
#include <hip/hip_bf16.h>
#include <cstdint>

// ---------------------------------------------------------------------------
// GATv2 encoder, fp32, correctness-first structure:
//   per layer: 2x GEMM (xl, xr) -> fused edge pass (logit, exp, scatter-add)
//              -> node epilogue (divide by denom, bias, activation)
// Softmax max-subtraction dropped (cancels algebraically; logits are tiny).
// Division by denom deferred to the node epilogue (distributes over the sum).
// ---------------------------------------------------------------------------

// ---- GEMM: Y[M,128] = X[M,128] @ W[128,128] + bias, fp32, 64x64 tiles ----
__global__ __launch_bounds__(256) void gemm_xw(const float* __restrict__ X,
                                               const float* __restrict__ W,
                                               const float* __restrict__ bias,
                                               float* __restrict__ Y, int M)
{
    __shared__ __align__(16) float Xs[64][129];   // +1 pad: conflict-free row reads
    __shared__ __align__(16) float Ws[128][64];
    const int bm = blockIdx.x, bn = blockIdx.y;
    const int tid = threadIdx.y * 16 + threadIdx.x;
    const int row0 = bm * 64;

    for (int idx = tid; idx < 64 * 128; idx += 256) {
        int r = idx >> 7, k = idx & 127;
        int row = row0 + r;
        Xs[r][k] = (row < M) ? X[(size_t)row * 128 + k] : 0.0f;
    }
    for (int idx = tid; idx < 128 * 64; idx += 256) {
        int k = idx >> 6, j = idx & 63;
        Ws[k][j] = W[(size_t)k * 128 + bn * 64 + j];
    }
    __syncthreads();

    const int ty = threadIdx.y, tx = threadIdx.x;
    float acc[4][4] = {};
#pragma unroll 8
    for (int k = 0; k < 128; ++k) {
        float4 b = *reinterpret_cast<const float4*>(&Ws[k][tx * 4]);
#pragma unroll
        for (int i = 0; i < 4; ++i) {
            float a = Xs[ty * 4 + i][k];
            acc[i][0] += a * b.x; acc[i][1] += a * b.y;
            acc[i][2] += a * b.z; acc[i][3] += a * b.w;
        }
    }

    const int col = bn * 64 + tx * 4;
    float4 bv = *reinterpret_cast<const float4*>(&bias[col]);
#pragma unroll
    for (int i = 0; i < 4; ++i) {
        int row = row0 + ty * 4 + i;
        if (row < M) {
            float4 o;
            o.x = acc[i][0] + bv.x; o.y = acc[i][1] + bv.y;
            o.z = acc[i][2] + bv.z; o.w = acc[i][3] + bv.w;
            *reinterpret_cast<float4*>(&Y[(size_t)row * 128 + col]) = o;
        }
    }
}

// ---- Fused edge pass: one wave per edge --------------------------------
// H*C == 128. Lane l handles feature indices l and l+64.
// H==4: head = idx>>5. Reduce within 32-lane halves.
// H==1: reduce across full wave.
template <int H, int C>
__global__ __launch_bounds__(256) void edge_pass(
    const float* __restrict__ xl, const float* __restrict__ xr,
    const int* __restrict__ src, const int* __restrict__ dst,
    int E_orig, int E_tot, const float* __restrict__ att,
    float* __restrict__ denom, float* __restrict__ acc)
{
    const int gid  = blockIdx.x * blockDim.x + threadIdx.x;
    const int wid  = gid >> 6;
    const int lane = threadIdx.x & 63;
    if (wid >= E_tot) return;

    int s, d;
    if (wid < E_orig) { s = src[wid]; d = dst[wid]; }
    else              { s = d = wid - E_orig; }     // self-loop

    const int i0 = lane, i1 = lane + 64;
    const float a0 = xl[(size_t)s * 128 + i0];
    const float a1 = xl[(size_t)s * 128 + i1];
    const float r0 = xr[(size_t)d * 128 + i0];
    const float r1 = xr[(size_t)d * 128 + i1];
    float t0 = a0 + r0, t1 = a1 + r1;
    t0 = t0 > 0.0f ? t0 : 0.2f * t0;               // leaky_relu
    t1 = t1 > 0.0f ? t1 : 0.2f * t1;
    float w0 = t0 * att[i0];
    float w1 = t1 * att[i1];

    if (H == 4) {
        // lanes 0-31: w0 -> head0, w1 -> head2 ; lanes 32-63: w0 -> head1, w1 -> head3
#pragma unroll
        for (int off = 1; off < 32; off <<= 1) {
            w0 += __shfl_xor(w0, off);
            w1 += __shfl_xor(w1, off);
        }
        const float p0 = __expf(w0);               // head (lane>>5)
        const float p1 = __expf(w1);               // head (lane>>5)+2
        if ((lane & 31) == 0) {
            const int half = lane >> 5;
            unsafeAtomicAdd(&denom[(size_t)d * 4 + half],     p0);
            unsafeAtomicAdd(&denom[(size_t)d * 4 + half + 2], p1);
        }
        unsafeAtomicAdd(&acc[(size_t)d * 128 + i0], a0 * p0);
        unsafeAtomicAdd(&acc[(size_t)d * 128 + i1], a1 * p1);
    } else {
        float w = w0 + w1;
#pragma unroll
        for (int off = 1; off < 64; off <<= 1) w += __shfl_xor(w, off);
        const float p = __expf(w);
        if (lane == 0) unsafeAtomicAdd(&denom[d], p);
        unsafeAtomicAdd(&acc[(size_t)d * 128 + i0], a0 * p);
        unsafeAtomicAdd(&acc[(size_t)d * 128 + i1], a1 * p);
    }
}

// ---- Node epilogues -----------------------------------------------------
__global__ __launch_bounds__(256) void node_finish1(
    const float* __restrict__ acc, const float* __restrict__ denom,
    const float* __restrict__ bias, float* __restrict__ h, int total)
{
    int idx = blockIdx.x * blockDim.x + threadIdx.x;
    if (idx >= total) return;
    int n = idx >> 7, i = idx & 127;
    float v = acc[idx] / denom[(size_t)n * 4 + (i >> 5)] + bias[i];
    h[idx] = v > 0.0f ? v : expm1f(v);             // ELU (alpha=1)
}

__global__ __launch_bounds__(256) void node_finish2(
    float* __restrict__ out, const float* __restrict__ denom,
    const float* __restrict__ bias, int total)
{
    int idx = blockIdx.x * blockDim.x + threadIdx.x;
    if (idx >= total) return;
    int n = idx >> 7, i = idx & 127;
    out[idx] = out[idx] / denom[n] + bias[i];      // heads=1 -> mean is identity
}

// ---------------------------------------------------------------------------
extern "C" void kernel_launch(void* const* d_in, const int* in_sizes, int n_in,
                              void* d_out, int out_size, void* d_ws, size_t ws_size,
                              hipStream_t stream)
{
    const float* x     = (const float*)d_in[0];
    const int*   ei    = (const int*)  d_in[1];
    const float* W1l   = (const float*)d_in[2];
    const float* b1l   = (const float*)d_in[3];
    const float* W1r   = (const float*)d_in[4];
    const float* b1r   = (const float*)d_in[5];
    const float* att1  = (const float*)d_in[6];
    const float* bias1 = (const float*)d_in[7];
    const float* W2l   = (const float*)d_in[8];
    const float* b2l   = (const float*)d_in[9];
    const float* W2r   = (const float*)d_in[10];
    const float* b2r   = (const float*)d_in[11];
    const float* att2  = (const float*)d_in[12];
    const float* bias2 = (const float*)d_in[13];
    float* out = (float*)d_out;

    const int N    = in_sizes[0] / 128;
    const int E    = in_sizes[1] / 2;
    const int Etot = E + N;
    const int* srcp = ei;         // edge_index[0]
    const int* dstp = ei + E;     // edge_index[1]

    float* xl     = (float*)d_ws;
    float* xr     = xl + (size_t)N * 128;
    float* hbuf   = xr + (size_t)N * 128;          // acc1, then h (in-place)
    float* denom1 = hbuf + (size_t)N * 128;        // [N,4]
    float* denom2 = denom1 + (size_t)N * 4;        // [N]

    // zero accumulators (ws and out are poisoned before every timed launch)
    hipMemsetAsync(hbuf,   0, (size_t)N * 128 * sizeof(float), stream);
    hipMemsetAsync(denom1, 0, (size_t)N * 4 * sizeof(float),   stream);
    hipMemsetAsync(denom2, 0, (size_t)N * sizeof(float),       stream);
    hipMemsetAsync(out,    0, (size_t)N * 128 * sizeof(float), stream);

    dim3 gB(16, 16);
    dim3 gG((N + 63) / 64, 2);
    const int eblocks = (Etot + 3) / 4;            // 4 waves (edges) per block
    const int total   = N * 128;
    const int nblocks = (total + 255) / 256;

    // ---- layer 1 ----
    gemm_xw<<<gG, gB, 0, stream>>>(x, W1l, b1l, xl, N);
    gemm_xw<<<gG, gB, 0, stream>>>(x, W1r, b1r, xr, N);
    edge_pass<4, 32><<<eblocks, 256, 0, stream>>>(xl, xr, srcp, dstp, E, Etot,
                                                  att1, denom1, hbuf);
    node_finish1<<<nblocks, 256, 0, stream>>>(hbuf, denom1, bias1, hbuf, total);

    // ---- layer 2 ----
    gemm_xw<<<gG, gB, 0, stream>>>(hbuf, W2l, b2l, xl, N);
    gemm_xw<<<gG, gB, 0, stream>>>(hbuf, W2r, b2r, xr, N);
    edge_pass<1, 128><<<eblocks, 256, 0, stream>>>(xl, xr, srcp, dstp, E, Etot,
                                                   att2, denom2, out);
    node_finish2<<<nblocks, 256, 0, stream>>>(out, denom2, bias2, total);
}

// Round 3
// 682.197 us; speedup vs baseline: 1.7827x; 1.7827x over previous
//
#include <hip/hip_runtime.h>
#include <hip/hip_bf16.h>
#include <cstdint>

// ---------------------------------------------------------------------------
// GATv2 encoder, fp32. Structure per launch:
//   build CSR by dst (histogram -> scan -> scatter)  [shared by both layers]
//   layer: 2x GEMM (xl, xr) -> one-wave-per-node gather/aggregate kernel
//          (logit, exp, weighted sum, normalize, bias, activation fused)
// Softmax max-subtraction dropped (cancels algebraically; logits are tiny).
// ---------------------------------------------------------------------------

// ---- GEMM: Y[M,128] = X[M,128] @ W[128,128] + bias, fp32, 64x64 tiles ----
__global__ __launch_bounds__(256) void gemm_xw(const float* __restrict__ X,
                                               const float* __restrict__ W,
                                               const float* __restrict__ bias,
                                               float* __restrict__ Y, int M)
{
    __shared__ __align__(16) float Xs[64][129];
    __shared__ __align__(16) float Ws[128][64];
    const int bm = blockIdx.x, bn = blockIdx.y;
    const int tid = threadIdx.y * 16 + threadIdx.x;
    const int row0 = bm * 64;

    for (int idx = tid; idx < 64 * 128; idx += 256) {
        int r = idx >> 7, k = idx & 127;
        int row = row0 + r;
        Xs[r][k] = (row < M) ? X[(size_t)row * 128 + k] : 0.0f;
    }
    for (int idx = tid; idx < 128 * 64; idx += 256) {
        int k = idx >> 6, j = idx & 63;
        Ws[k][j] = W[(size_t)k * 128 + bn * 64 + j];
    }
    __syncthreads();

    const int ty = threadIdx.y, tx = threadIdx.x;
    float acc[4][4] = {};
#pragma unroll 8
    for (int k = 0; k < 128; ++k) {
        float4 b = *reinterpret_cast<const float4*>(&Ws[k][tx * 4]);
#pragma unroll
        for (int i = 0; i < 4; ++i) {
            float a = Xs[ty * 4 + i][k];
            acc[i][0] += a * b.x; acc[i][1] += a * b.y;
            acc[i][2] += a * b.z; acc[i][3] += a * b.w;
        }
    }

    const int col = bn * 64 + tx * 4;
    float4 bv = *reinterpret_cast<const float4*>(&bias[col]);
#pragma unroll
    for (int i = 0; i < 4; ++i) {
        int row = row0 + ty * 4 + i;
        if (row < M) {
            float4 o;
            o.x = acc[i][0] + bv.x; o.y = acc[i][1] + bv.y;
            o.z = acc[i][2] + bv.z; o.w = acc[i][3] + bv.w;
            *reinterpret_cast<float4*>(&Y[(size_t)row * 128 + col]) = o;
        }
    }
}

// ---- CSR build ----------------------------------------------------------
__global__ __launch_bounds__(256) void hist_kernel(const int* __restrict__ dst, int E,
                                                   int* __restrict__ count)
{
    for (int i = blockIdx.x * blockDim.x + threadIdx.x; i < E;
         i += gridDim.x * blockDim.x)
        atomicAdd(&count[dst[i]], 1);
}

// single-workgroup exclusive scan of (count[i] + 1)  [+1 = self-loop]
__global__ __launch_bounds__(1024) void scan_offsets(const int* __restrict__ count,
                                                     int* __restrict__ offset,
                                                     int* __restrict__ cursor, int N)
{
    __shared__ int wsum[16];
    __shared__ int carry_s;
    const int tid = threadIdx.x;
    const int lane = tid & 63, w = tid >> 6;
    if (tid == 0) carry_s = 0;
    __syncthreads();
    for (int base = 0; base < N; base += 1024) {
        int i = base + tid;
        int v = (i < N) ? (count[i] + 1) : 0;
        int x = v;
#pragma unroll
        for (int off = 1; off < 64; off <<= 1) {
            int y = __shfl_up(x, off);
            if (lane >= off) x += y;
        }
        if (lane == 63) wsum[w] = x;
        __syncthreads();
        if (tid < 16) {
            int s2 = wsum[tid];
#pragma unroll
            for (int off = 1; off < 16; off <<= 1) {
                int y = __shfl_up(s2, off);
                if (tid >= off) s2 += y;
            }
            wsum[tid] = s2;
        }
        __syncthreads();
        int carry = carry_s;
        int inc = x + ((w > 0) ? wsum[w - 1] : 0) + carry;
        if (i < N) { offset[i] = inc - v; cursor[i] = inc - v; }
        __syncthreads();                 // all reads of carry_s/wsum done
        if (tid == 1023) carry_s = inc;
        __syncthreads();
    }
    if (tid == 0) offset[N] = carry_s;
}

__global__ __launch_bounds__(256) void scatter_kernel(const int* __restrict__ src,
                                                      const int* __restrict__ dst, int E,
                                                      int* __restrict__ cursor,
                                                      int* __restrict__ srcids)
{
    for (int i = blockIdx.x * blockDim.x + threadIdx.x; i < E;
         i += gridDim.x * blockDim.x) {
        int p = atomicAdd(&cursor[dst[i]], 1);
        srcids[p] = src[i];
    }
}

__global__ __launch_bounds__(256) void selfloop_kernel(int* __restrict__ cursor,
                                                       int* __restrict__ srcids, int N)
{
    int i = blockIdx.x * blockDim.x + threadIdx.x;
    if (i < N) {
        int p = atomicAdd(&cursor[i], 1);
        srcids[p] = i;
    }
}

// ---- Fused per-node aggregation: one wave per node ----------------------
// Lane l holds features l and l+64. HEADS==4: head = feat>>5, reduce within
// 32-lane halves. HEADS==1: reduce across full wave.
template <int HEADS, bool ELU>
__global__ __launch_bounds__(256) void gat_aggregate(
    const float* __restrict__ xl, const float* __restrict__ xr,
    const int* __restrict__ offset, const int* __restrict__ srcids,
    const float* __restrict__ att, const float* __restrict__ bias,
    float* __restrict__ out, int N)
{
    const int wid  = (blockIdx.x * blockDim.x + threadIdx.x) >> 6;
    const int lane = threadIdx.x & 63;
    if (wid >= N) return;

    const int i0 = lane, i1 = lane + 64;
    const float r0  = xr[(size_t)wid * 128 + i0];
    const float r1  = xr[(size_t)wid * 128 + i1];
    const float av0 = att[i0], av1 = att[i1];

    float acc0 = 0.0f, acc1 = 0.0f, d0 = 0.0f, d1 = 0.0f;
    const int beg = offset[wid], end = offset[wid + 1];

    int s_next = (beg < end) ? srcids[beg] : 0;
    for (int i = beg; i < end; ++i) {
        const int s = s_next;
        if (i + 1 < end) s_next = srcids[i + 1];
        const float* xs = xl + (size_t)s * 128;
        const float a0 = xs[i0];
        const float a1 = xs[i1];
        float t0 = a0 + r0, t1 = a1 + r1;
        t0 = t0 > 0.0f ? t0 : 0.2f * t0;           // leaky_relu
        t1 = t1 > 0.0f ? t1 : 0.2f * t1;
        float w0 = t0 * av0, w1 = t1 * av1;
        if (HEADS == 4) {
#pragma unroll
            for (int off = 1; off < 32; off <<= 1) {
                w0 += __shfl_xor(w0, off);
                w1 += __shfl_xor(w1, off);
            }
            const float p0 = __expf(w0);
            const float p1 = __expf(w1);
            acc0 += a0 * p0; acc1 += a1 * p1;
            d0 += p0; d1 += p1;
        } else {
            float ww = w0 + w1;
#pragma unroll
            for (int off = 1; off < 64; off <<= 1) ww += __shfl_xor(ww, off);
            const float p = __expf(ww);
            acc0 += a0 * p; acc1 += a1 * p;
            d0 += p;
        }
    }

    float v0, v1;
    if (HEADS == 4) { v0 = acc0 / d0 + bias[i0]; v1 = acc1 / d1 + bias[i1]; }
    else           { v0 = acc0 / d0 + bias[i0]; v1 = acc1 / d0 + bias[i1]; }
    if (ELU) {
        v0 = v0 > 0.0f ? v0 : expm1f(v0);
        v1 = v1 > 0.0f ? v1 : expm1f(v1);
    }
    out[(size_t)wid * 128 + i0] = v0;
    out[(size_t)wid * 128 + i1] = v1;
}

// ---------------------------------------------------------------------------
extern "C" void kernel_launch(void* const* d_in, const int* in_sizes, int n_in,
                              void* d_out, int out_size, void* d_ws, size_t ws_size,
                              hipStream_t stream)
{
    const float* x     = (const float*)d_in[0];
    const int*   ei    = (const int*)  d_in[1];
    const float* W1l   = (const float*)d_in[2];
    const float* b1l   = (const float*)d_in[3];
    const float* W1r   = (const float*)d_in[4];
    const float* b1r   = (const float*)d_in[5];
    const float* att1  = (const float*)d_in[6];
    const float* bias1 = (const float*)d_in[7];
    const float* W2l   = (const float*)d_in[8];
    const float* b2l   = (const float*)d_in[9];
    const float* W2r   = (const float*)d_in[10];
    const float* b2r   = (const float*)d_in[11];
    const float* att2  = (const float*)d_in[12];
    const float* bias2 = (const float*)d_in[13];
    float* out = (float*)d_out;

    const int N    = in_sizes[0] / 128;
    const int E    = in_sizes[1] / 2;
    const int Etot = E + N;
    const int* srcp = ei;         // edge_index[0]
    const int* dstp = ei + E;     // edge_index[1]

    // ---- workspace layout: int region first, then 16B-aligned float region
    int* count  = (int*)d_ws;                 // [N]
    int* offset = count + N;                  // [N+1]
    int* cursor = offset + N + 1;             // [N]
    int* srcids = cursor + N;                 // [Etot]
    size_t int_elems = (size_t)3 * N + 1 + Etot;
    int_elems = (int_elems + 3) & ~(size_t)3;
    float* xl   = (float*)d_ws + int_elems;   // [N*128]
    float* xr   = xl + (size_t)N * 128;       // [N*128]
    float* hbuf = xr + (size_t)N * 128;       // [N*128]

    // ---- build CSR by dst (self-loops appended per node) ----
    hipMemsetAsync(count, 0, (size_t)N * sizeof(int), stream);
    hist_kernel<<<2048, 256, 0, stream>>>(dstp, E, count);
    scan_offsets<<<1, 1024, 0, stream>>>(count, offset, cursor, N);
    scatter_kernel<<<2048, 256, 0, stream>>>(srcp, dstp, E, cursor, srcids);
    selfloop_kernel<<<(N + 255) / 256, 256, 0, stream>>>(cursor, srcids, N);

    dim3 gB(16, 16);
    dim3 gG((N + 63) / 64, 2);
    const int ablocks = (N + 3) / 4;          // 4 nodes (waves) per block

    // ---- layer 1 ----
    gemm_xw<<<gG, gB, 0, stream>>>(x, W1l, b1l, xl, N);
    gemm_xw<<<gG, gB, 0, stream>>>(x, W1r, b1r, xr, N);
    gat_aggregate<4, true><<<ablocks, 256, 0, stream>>>(xl, xr, offset, srcids,
                                                        att1, bias1, hbuf, N);
    // ---- layer 2 ----
    gemm_xw<<<gG, gB, 0, stream>>>(hbuf, W2l, b2l, xl, N);
    gemm_xw<<<gG, gB, 0, stream>>>(hbuf, W2r, b2r, xr, N);
    gat_aggregate<1, false><<<ablocks, 256, 0, stream>>>(xl, xr, offset, srcids,
                                                         att2, bias2, out, N);
}

// Round 6
// 658.032 us; speedup vs baseline: 1.8482x; 1.0367x over previous
//
#include <hip/hip_runtime.h>
#include <hip/hip_bf16.h>
#include <cstdint>

// ---------------------------------------------------------------------------
// GATv2 encoder. Structure per launch:
//   build CSR by dst (histogram -> scan -> scatter)  [shared by both layers]
//   layer: 2x GEMM (xl->bf16, xr->fp32) -> one-wave-per-node aggregate
// Lane l owns features {2l, 2l+1} (same head) -> single-value shuffle reduce.
// xl stored bf16: halves gather traffic; xr/h/out stay fp32.
// Softmax max-subtraction dropped (cancels algebraically; logits are tiny).
// ---------------------------------------------------------------------------

// ---- GEMM: Y[M,128] = X[M,128] @ W[128,128] + bias, 64x64 tiles ----------
template <typename TO>
__global__ __launch_bounds__(256) void gemm_xw(const float* __restrict__ X,
                                               const float* __restrict__ W,
                                               const float* __restrict__ bias,
                                               TO* __restrict__ Y, int M)
{
    __shared__ __align__(16) float Xs[64][129];
    __shared__ __align__(16) float Ws[128][64];
    const int bm = blockIdx.x, bn = blockIdx.y;
    const int tid = threadIdx.y * 16 + threadIdx.x;
    const int row0 = bm * 64;

    for (int idx = tid; idx < 64 * 128; idx += 256) {
        int r = idx >> 7, k = idx & 127;
        int row = row0 + r;
        Xs[r][k] = (row < M) ? X[(size_t)row * 128 + k] : 0.0f;
    }
    for (int idx = tid; idx < 128 * 64; idx += 256) {
        int k = idx >> 6, j = idx & 63;
        Ws[k][j] = W[(size_t)k * 128 + bn * 64 + j];
    }
    __syncthreads();

    const int ty = threadIdx.y, tx = threadIdx.x;
    float acc[4][4] = {};
#pragma unroll 8
    for (int k = 0; k < 128; ++k) {
        float4 b = *reinterpret_cast<const float4*>(&Ws[k][tx * 4]);
#pragma unroll
        for (int i = 0; i < 4; ++i) {
            float a = Xs[ty * 4 + i][k];
            acc[i][0] += a * b.x; acc[i][1] += a * b.y;
            acc[i][2] += a * b.z; acc[i][3] += a * b.w;
        }
    }

    const int col = bn * 64 + tx * 4;
    float4 bv = *reinterpret_cast<const float4*>(&bias[col]);
#pragma unroll
    for (int i = 0; i < 4; ++i) {
        int row = row0 + ty * 4 + i;
        if (row < M) {
            float o[4] = { acc[i][0] + bv.x, acc[i][1] + bv.y,
                           acc[i][2] + bv.z, acc[i][3] + bv.w };
            if constexpr (__is_same(TO, float)) {
                float4 v = { o[0], o[1], o[2], o[3] };
                *reinterpret_cast<float4*>(&Y[(size_t)row * 128 + col]) = v;
            } else {   // bf16 output, 4 elems = 8B store
                union { ushort4 u; __hip_bfloat16 b[4]; } pk;
                pk.b[0] = __float2bfloat16(o[0]);
                pk.b[1] = __float2bfloat16(o[1]);
                pk.b[2] = __float2bfloat16(o[2]);
                pk.b[3] = __float2bfloat16(o[3]);
                *reinterpret_cast<ushort4*>(&Y[(size_t)row * 128 + col]) = pk.u;
            }
        }
    }
}

// ---- CSR build ----------------------------------------------------------
__global__ __launch_bounds__(256) void hist_kernel(const int* __restrict__ dst, int E,
                                                   int* __restrict__ count)
{
    for (int i = blockIdx.x * blockDim.x + threadIdx.x; i < E;
         i += gridDim.x * blockDim.x)
        atomicAdd(&count[dst[i]], 1);
}

// single-workgroup exclusive scan of (count[i] + 1)  [+1 = self-loop]
__global__ __launch_bounds__(1024) void scan_offsets(const int* __restrict__ count,
                                                     int* __restrict__ offset,
                                                     int* __restrict__ cursor, int N)
{
    __shared__ int wsum[16];
    __shared__ int carry_s;
    const int tid = threadIdx.x;
    const int lane = tid & 63, w = tid >> 6;
    if (tid == 0) carry_s = 0;
    __syncthreads();
    for (int base = 0; base < N; base += 1024) {
        int i = base + tid;
        int v = (i < N) ? (count[i] + 1) : 0;
        int x = v;
#pragma unroll
        for (int off = 1; off < 64; off <<= 1) {
            int y = __shfl_up(x, off);
            if (lane >= off) x += y;
        }
        if (lane == 63) wsum[w] = x;
        __syncthreads();
        if (tid < 16) {
            int s2 = wsum[tid];
#pragma unroll
            for (int off = 1; off < 16; off <<= 1) {
                int y = __shfl_up(s2, off);
                if (tid >= off) s2 += y;
            }
            wsum[tid] = s2;
        }
        __syncthreads();
        int carry = carry_s;
        int inc = x + ((w > 0) ? wsum[w - 1] : 0) + carry;
        if (i < N) { offset[i] = inc - v; cursor[i] = inc - v; }
        __syncthreads();
        if (tid == 1023) carry_s = inc;
        __syncthreads();
    }
    if (tid == 0) offset[N] = carry_s;
}

__global__ __launch_bounds__(256) void scatter_kernel(const int* __restrict__ src,
                                                      const int* __restrict__ dst, int E,
                                                      int* __restrict__ cursor,
                                                      int* __restrict__ srcids)
{
    for (int i = blockIdx.x * blockDim.x + threadIdx.x; i < E;
         i += gridDim.x * blockDim.x) {
        int p = atomicAdd(&cursor[dst[i]], 1);
        srcids[p] = src[i];
    }
}

__global__ __launch_bounds__(256) void selfloop_kernel(int* __restrict__ cursor,
                                                       int* __restrict__ srcids, int N)
{
    int i = blockIdx.x * blockDim.x + threadIdx.x;
    if (i < N) {
        int p = atomicAdd(&cursor[i], 1);
        srcids[p] = i;
    }
}

// ---- Fused per-node aggregation: one wave per node ----------------------
// Lane l owns features {2l, 2l+1} (both in head l>>4 when HEADS==4).
// xl is bf16-packed: one u32 load per edge per lane.
template <int HEADS, bool ELU>
__global__ __launch_bounds__(256) void gat_aggregate(
    const uint32_t* __restrict__ xl2,   // [N][64] packed bf16 pairs
    const float* __restrict__ xr,
    const int* __restrict__ offset, const int* __restrict__ srcids,
    const float* __restrict__ att, const float* __restrict__ bias,
    float* __restrict__ out, int N)
{
    const int wid  = (blockIdx.x * blockDim.x + threadIdx.x) >> 6;
    const int lane = threadIdx.x & 63;
    if (wid >= N) return;

    const int f0 = lane * 2;
    const float2 rr = *reinterpret_cast<const float2*>(&xr[(size_t)wid * 128 + f0]);
    const float av0 = att[f0], av1 = att[f0 + 1];

    float acc0 = 0.0f, acc1 = 0.0f, d = 0.0f;
    const int beg = offset[wid], end = offset[wid + 1];

    int s_next = (beg < end) ? srcids[beg] : 0;
    for (int i = beg; i < end; ++i) {
        const int s = s_next;
        if (i + 1 < end) s_next = srcids[i + 1];
        const uint32_t v = xl2[(size_t)s * 64 + lane];
        const float a0 = __uint_as_float(v << 16);
        const float a1 = __uint_as_float(v & 0xFFFF0000u);
        float t0 = a0 + rr.x, t1 = a1 + rr.y;
        t0 = t0 > 0.0f ? t0 : 0.2f * t0;           // leaky_relu
        t1 = t1 > 0.0f ? t1 : 0.2f * t1;
        float w = t0 * av0 + t1 * av1;
        if (HEADS == 4) {
#pragma unroll
            for (int off = 1; off < 16; off <<= 1) w += __shfl_xor(w, off);
        } else {
#pragma unroll
            for (int off = 1; off < 64; off <<= 1) w += __shfl_xor(w, off);
        }
        const float p = __expf(w);
        acc0 += a0 * p; acc1 += a1 * p; d += p;
    }

    float v0 = acc0 / d + bias[f0];
    float v1 = acc1 / d + bias[f0 + 1];
    if (ELU) {
        v0 = v0 > 0.0f ? v0 : expm1f(v0);
        v1 = v1 > 0.0f ? v1 : expm1f(v1);
    }
    float2 o = { v0, v1 };
    *reinterpret_cast<float2*>(&out[(size_t)wid * 128 + f0]) = o;
}

// ---------------------------------------------------------------------------
extern "C" void kernel_launch(void* const* d_in, const int* in_sizes, int n_in,
                              void* d_out, int out_size, void* d_ws, size_t ws_size,
                              hipStream_t stream)
{
    const float* x     = (const float*)d_in[0];
    const int*   ei    = (const int*)  d_in[1];
    const float* W1l   = (const float*)d_in[2];
    const float* b1l   = (const float*)d_in[3];
    const float* W1r   = (const float*)d_in[4];
    const float* b1r   = (const float*)d_in[5];
    const float* att1  = (const float*)d_in[6];
    const float* bias1 = (const float*)d_in[7];
    const float* W2l   = (const float*)d_in[8];
    const float* b2l   = (const float*)d_in[9];
    const float* W2r   = (const float*)d_in[10];
    const float* b2r   = (const float*)d_in[11];
    const float* att2  = (const float*)d_in[12];
    const float* bias2 = (const float*)d_in[13];
    float* out = (float*)d_out;

    const int N    = in_sizes[0] / 128;
    const int E    = in_sizes[1] / 2;
    const int Etot = E + N;
    const int* srcp = ei;         // edge_index[0]
    const int* dstp = ei + E;     // edge_index[1]

    // ---- workspace layout ------------------------------------------------
    int* count  = (int*)d_ws;                 // [N]
    int* offset = count + N;                  // [N+1]
    int* cursor = offset + N + 1;             // [N]
    int* srcids = cursor + N;                 // [Etot]
    size_t int_elems = (size_t)3 * N + 1 + Etot;
    int_elems = (int_elems + 3) & ~(size_t)3;         // 16B align
    float* xr   = (float*)d_ws + int_elems;   // [N*128] f32
    float* hbuf = xr + (size_t)N * 128;       // [N*128] f32
    __hip_bfloat16* xl = (__hip_bfloat16*)(hbuf + (size_t)N * 128);  // [N*128] bf16
    uint32_t* xl2 = (uint32_t*)xl;

    // ---- build CSR by dst (self-loops appended per node) ----
    hipMemsetAsync(count, 0, (size_t)N * sizeof(int), stream);
    hist_kernel<<<2048, 256, 0, stream>>>(dstp, E, count);
    scan_offsets<<<1, 1024, 0, stream>>>(count, offset, cursor, N);
    scatter_kernel<<<2048, 256, 0, stream>>>(srcp, dstp, E, cursor, srcids);
    selfloop_kernel<<<(N + 255) / 256, 256, 0, stream>>>(cursor, srcids, N);

    dim3 gB(16, 16);
    dim3 gG((N + 63) / 64, 2);
    const int ablocks = (N + 3) / 4;          // 4 nodes (waves) per block

    // ---- layer 1 ----
    gemm_xw<__hip_bfloat16><<<gG, gB, 0, stream>>>(x, W1l, b1l, xl, N);
    gemm_xw<float><<<gG, gB, 0, stream>>>(x, W1r, b1r, xr, N);
    gat_aggregate<4, true><<<ablocks, 256, 0, stream>>>(xl2, xr, offset, srcids,
                                                        att1, bias1, hbuf, N);
    // ---- layer 2 ----
    gemm_xw<__hip_bfloat16><<<gG, gB, 0, stream>>>(hbuf, W2l, b2l, xl, N);
    gemm_xw<float><<<gG, gB, 0, stream>>>(hbuf, W2r, b2r, xr, N);
    gat_aggregate<1, false><<<ablocks, 256, 0, stream>>>(xl2, xr, offset, srcids,
                                                         att2, bias2, out, N);
}